// Round 2
// baseline (512.963 us; speedup 1.0000x reference)
//
#include <hip/hip_runtime.h>
#include <math.h>

// Problem constants
#define BATCH 64
#define LDIM  256
#define HDIM  1024
#define DDIM  1024
#define BAND  16
#define MNZ   33          // 2*BAND+1
#define NN    (DDIM*MNZ)  // 33792

typedef float v4f __attribute__((ext_vector_type(4)));

// ---------------------------------------------------------------------------
// K1: h = gelu(z @ W1 + b1), written TRANSPOSED: ht[k][b]  (k-major, 64 floats/row)
// grid (4, 64) blocks x 256 threads; block (jt, b) computes h[b, jt*256 .. +255]
// ---------------------------------------------------------------------------
__global__ __launch_bounds__(256) void k1_h(const float* __restrict__ z,
                                            const float* __restrict__ W1,
                                            const float* __restrict__ b1,
                                            float* __restrict__ ht) {
    __shared__ float zs[LDIM];
    const int t = threadIdx.x;
    const int b = blockIdx.y;
    const int j = blockIdx.x * 256 + t;
    zs[t] = z[b * LDIM + t];
    __syncthreads();
    float acc = b1[j];
#pragma unroll 8
    for (int l = 0; l < LDIM; ++l)
        acc = fmaf(zs[l], W1[l * HDIM + j], acc);
    // exact (erf) GELU
    float g = 0.5f * acc * (1.0f + erff(acc * 0.70710678118654752f));
    ht[(size_t)j * BATCH + b] = g;   // transposed scatter (tiny: 256 KB total)
}

// ---------------------------------------------------------------------------
// K2: v = h @ W2 + b2   (v: [64][33792], b-major)
// grid 528 blocks x 256 threads. Block = 64 columns x 4 batch-groups of 16.
// Wave w handles batches [w*16, w*16+16) for cols [blk*64, blk*64+64).
// Per k: 1 coalesced W2 load (L1-shared across the 4 waves),
//        1 wave-uniform 64B ht read (scalar-pipe eligible), 16 fmac.
// ---------------------------------------------------------------------------
__global__ __launch_bounds__(256) void k2_v(const float* __restrict__ W2,
                                            const float* __restrict__ b2,
                                            const float* __restrict__ ht,
                                            float* __restrict__ v) {
    const int lane = threadIdx.x & 63;
    const int col  = blockIdx.x * 64 + lane;
    // wave-uniform batch group (waves are contiguous 64-thread chunks)
    const int bg = __builtin_amdgcn_readfirstlane((int)(threadIdx.x >> 6));
    const int b0 = bg * 16;

    float acc[16];
#pragma unroll
    for (int j = 0; j < 16; ++j) acc[j] = 0.0f;

    const float* __restrict__ wp = W2 + col;
    const float* __restrict__ hp = ht + b0;   // uniform base

    for (int kk = 0; kk < HDIM; ++kk) {
        const float w = wp[(size_t)kk * NN];
        const float4* __restrict__ h4 = (const float4*)(hp + kk * BATCH);
        const float4 a = h4[0], b = h4[1], c = h4[2], d = h4[3];
        acc[0]  = fmaf(a.x, w, acc[0]);
        acc[1]  = fmaf(a.y, w, acc[1]);
        acc[2]  = fmaf(a.z, w, acc[2]);
        acc[3]  = fmaf(a.w, w, acc[3]);
        acc[4]  = fmaf(b.x, w, acc[4]);
        acc[5]  = fmaf(b.y, w, acc[5]);
        acc[6]  = fmaf(b.z, w, acc[6]);
        acc[7]  = fmaf(b.w, w, acc[7]);
        acc[8]  = fmaf(c.x, w, acc[8]);
        acc[9]  = fmaf(c.y, w, acc[9]);
        acc[10] = fmaf(c.z, w, acc[10]);
        acc[11] = fmaf(c.w, w, acc[11]);
        acc[12] = fmaf(d.x, w, acc[12]);
        acc[13] = fmaf(d.y, w, acc[13]);
        acc[14] = fmaf(d.z, w, acc[14]);
        acc[15] = fmaf(d.w, w, acc[15]);
    }

    const float bias = b2[col];
#pragma unroll
    for (int j = 0; j < 16; ++j)
        v[(size_t)(b0 + j) * NN + col] = acc[j] + bias;
}

// ---------------------------------------------------------------------------
// K3: out[b,i,j] = (|i-j|<=16) ? 0.5*(v[b,i,j-lo(i)] + v[b,j,i-lo(j)]) + (i==j) : 0
// grid 16384 blocks x 256 threads; each block writes 4 full rows (4 KB each),
// one float4 per thread per row (perfectly coalesced, nontemporal).
// ---------------------------------------------------------------------------
__global__ __launch_bounds__(256) void k3_out(const float* __restrict__ v,
                                              float* __restrict__ out) {
    const int tid = threadIdx.x;
#pragma unroll
    for (int r = 0; r < 4; ++r) {
        const int rowid = blockIdx.x * 4 + r;
        const int b = rowid >> 10;
        const int i = rowid & (DDIM - 1);
        const int j0 = tid * 4;
        v4f res = (v4f){0.f, 0.f, 0.f, 0.f};
        if (j0 + 3 >= i - BAND && j0 <= i + BAND) {
            const int lo_i = (i > BAND) ? (i - BAND) : 0;
            const float* __restrict__ vb = v + (size_t)b * NN;
#pragma unroll
            for (int c = 0; c < 4; ++c) {
                const int j = j0 + c;
                const int d = j - i;
                float x = 0.0f;
                if (d >= -BAND && d <= BAND) {
                    const int lo_j = (j > BAND) ? (j - BAND) : 0;
                    x = 0.5f * (vb[i * MNZ + (j - lo_i)] + vb[j * MNZ + (i - lo_j)]);
                    if (d == 0) x += 1.0f;
                }
                res[c] = x;
            }
        }
        v4f* dst = ((v4f*)out) + (size_t)rowid * (DDIM / 4) + tid;
        __builtin_nontemporal_store(res, dst);
    }
}

// ---------------------------------------------------------------------------
extern "C" void kernel_launch(void* const* d_in, const int* in_sizes, int n_in,
                              void* d_out, int out_size, void* d_ws, size_t ws_size,
                              hipStream_t stream) {
    const float* z  = (const float*)d_in[0];
    // d_in[1] = mask (unused: band structure is closed-form)
    const float* W1 = (const float*)d_in[2];
    const float* b1 = (const float*)d_in[3];
    const float* W2 = (const float*)d_in[4];
    const float* b2 = (const float*)d_in[5];
    // d_in[6] = idx (unused)

    float* ht = (float*)d_ws;                 // 64*1024 floats, transposed h
    float* v  = ht + BATCH * HDIM;            // 64*33792 floats
    float* out = (float*)d_out;

    k1_h  <<<dim3(4, 64), 256, 0, stream>>>(z, W1, b1, ht);
    k2_v  <<<dim3(NN / 64), 256, 0, stream>>>(W2, b2, ht, v);
    k3_out<<<dim3((BATCH * DDIM) / 4), 256, 0, stream>>>(v, out);
}